// Round 23
// baseline (98.558 us; speedup 1.0000x reference)
//
#include <hip/hip_runtime.h>

#define DIN 512
#define DOUT 512
#define BM 128

typedef int v4i __attribute__((ext_vector_type(4)));
typedef float v4f __attribute__((ext_vector_type(4)));

#define WAITVM(n) asm volatile("s_waitcnt vmcnt(" #n ")" ::: "memory")
#define WAITLGKM0() asm volatile("s_waitcnt lgkmcnt(0)" ::: "memory")

// exact-divide quantize (weights/bias path, matches ref bit-for-bit)
__device__ __forceinline__ int q8f(float v, float s) {
    int i = (int)rintf(v / s);
    i = i < -128 ? -128 : (i > 127 ? 127 : i);
    return i & 255;
}
// multiply-by-reciprocal quantize (activation path; flip prob ~2^-22)
__device__ __forceinline__ int q8m(float v, float inv) {
    int i = (int)rintf(v * inv);
    i = i < -128 ? -128 : (i > 127 ? 127 : i);
    return i & 255;
}

// ---------------- Kernel 1: global absmax of x ----------------
__global__ void absmax_kernel(const float4* __restrict__ x4, unsigned* __restrict__ amax, int n4) {
    float m = 0.f;
    int stride = gridDim.x * blockDim.x;
    for (int i = blockIdx.x * blockDim.x + threadIdx.x; i < n4; i += stride) {
        float4 v = x4[i];
        m = fmaxf(m, fmaxf(fmaxf(fabsf(v.x), fabsf(v.y)), fmaxf(fabsf(v.z), fabsf(v.w))));
    }
#pragma unroll
    for (int off = 32; off; off >>= 1) m = fmaxf(m, __shfl_xor(m, off));
    __shared__ float sm[4];
    int lane = threadIdx.x & 63, w = threadIdx.x >> 6;
    if (lane == 0) sm[w] = m;
    __syncthreads();
    if (threadIdx.x == 0) {
        m = fmaxf(fmaxf(sm[0], sm[1]), fmaxf(sm[2], sm[3]));
        atomicMax(amax, __float_as_uint(m));  // positive floats: uint compare == float compare
    }
}

// ---------------- Kernel 2: weight quant -> frag-linear wq8 (+ amax zero-init) ----------------
// wq8 byte(og,ks,kq,r,b) = og*8192 + ks*1024 + kq*256 + r*16 + b ==> frag (og,ks)
// is CONTIGUOUS 1KB at wq8 + og*8192 + ks*1024 + lane*16. (R12-validated)
__global__ void quantw_kernel(const float* __restrict__ w, char* __restrict__ wq8,
                              float* __restrict__ wsc, unsigned* __restrict__ amax) {
    int gid = blockIdx.x * blockDim.x + threadIdx.x;
    if (gid == 0) *amax = 0u;   // zero-init; absmax launches after quantw on same stream
    int row = gid >> 6, lane = gid & 63;
    const float4* r4 = (const float4*)(w + (long)row * DIN);
    float4 a = r4[lane * 2];
    float4 b = r4[lane * 2 + 1];
    float m = fmaxf(fmaxf(fmaxf(fabsf(a.x), fabsf(a.y)), fabsf(a.z)),
                    fmaxf(fmaxf(fabsf(a.w), fabsf(b.x)),
                          fmaxf(fmaxf(fabsf(b.y), fabsf(b.z)), fabsf(b.w))));
#pragma unroll
    for (int off = 32; off; off >>= 1) m = fmaxf(m, __shfl_xor(m, off));
    float s = m / 127.0f;
    int lo = q8f(a.x, s) | (q8f(a.y, s) << 8) | (q8f(a.z, s) << 16) | (q8f(a.w, s) << 24);
    int hi = q8f(b.x, s) | (q8f(b.y, s) << 8) | (q8f(b.z, s) << 16) | (q8f(b.w, s) << 24);
    {
        int og = row >> 4, r = row & 15;
        int ks = lane >> 3, kq = (lane >> 1) & 3, bo = (lane & 1) * 8;
        *(int2*)(wq8 + og * 8192 + ks * 1024 + kq * 256 + r * 16 + bo) = make_int2(lo, hi);
    }
    if (lane == 0) wsc[row] = s;
}

// ---------------- Kernel 3: R22 skeleton scaled to BM=128 @ 1024 thr ----------------
// 512 blocks x 1024 thr (16 waves, 4m x 4oc; wave tile 32m x 128oc, acc 64 VGPR).
// Halves wq8 L2 re-read traffic (256->128 MB) and total barrier count vs R22.
// Per kstep/wave: 2 x-float4 loads + 2 contiguous-1KB wq8 DMAs; ladder
// (4,4),(6,4)x5,(4,2),(0). LDS: xl 2x8KB + wl 2x32KB + 4KB = 84KB -> 1 blk/CU
// (16 waves/CU, same residency as R22's 2x8). Epilogue: transposed full-line
// nt stores over 4 rounds (wm in 0..3), 16KB contiguous per instr round.
__global__ __launch_bounds__(1024, 2) void gemm_kernel(
    const float* __restrict__ x, const char* __restrict__ wq8,
    const float* __restrict__ wsc, const float* __restrict__ bias,
    const unsigned* __restrict__ amax, float* __restrict__ out) {
    __shared__ char xl[2][BM * 64];             // 2 x 8 KB x slices
    __shared__ char wl[2][DOUT * 64];           // 2 x 32 KB w slices; reused as ostage
    __shared__ __align__(16) float bsl[512];
    __shared__ __align__(16) float bql[512];
    const int t = threadIdx.x, lane = t & 63, wid = t >> 6;
    const int wm = wid >> 2, wn = wid & 3;
    const long rbase = (long)(gridDim.x - 1 - blockIdx.x) * BM;   // reverse: L3 recency
    const float as = __uint_as_float(*amax) / 127.0f;
    const float inv_as = 1.0f / as;

    // fold quantb: half the threads, one oc each
    if (t < 512) {
        float s0 = as * wsc[t];
        bsl[t] = s0;
        bql[t] = rintf(bias[t] / s0) * s0;
    }

    // x staging geometry: thread t -> row t>>3 (128 rows), float4-pair col (t&7)*2
    const int xrow = t >> 3, xc = t & 7;
    const float4* xg = (const float4*)(x + (rbase + xrow) * DIN) + xc * 2;
    const int xw_off = ((xrow >> 4) * 64 + (xc >> 1) * 16 + (xrow & 15)) * 16 + (xc & 1) * 8;

    // w DMA geometry: wave wid stages og chunks wid*2, wid*2+1 (contiguous 1KB each)
    const char* wgsrc = wq8 + (wid * 2) * 8192 + lane * 16;

    float4 xv[2][2];
    v4i acc[2][8] = {};

#define LOADX(n, s) { const float4* p_ = xg + (n) * 16; xv[s][0] = p_[0]; xv[s][1] = p_[1]; }
#define DMAW(n, b) { _Pragma("unroll") for (int jj = 0; jj < 2; jj++) \
    __builtin_amdgcn_global_load_lds( \
        (const __attribute__((address_space(1))) unsigned*)(wgsrc + jj * 8192 + (n) * 1024), \
        (__attribute__((address_space(3))) unsigned*)(wl[b] + (wid * 2 + jj) * 1024), 16, 0, 0); }
#define QUANTX(s, b) { \
    int lo_ = q8m(xv[s][0].x, inv_as) | (q8m(xv[s][0].y, inv_as) << 8) | \
              (q8m(xv[s][0].z, inv_as) << 16) | (q8m(xv[s][0].w, inv_as) << 24); \
    int hi_ = q8m(xv[s][1].x, inv_as) | (q8m(xv[s][1].y, inv_as) << 8) | \
              (q8m(xv[s][1].z, inv_as) << 16) | (q8m(xv[s][1].w, inv_as) << 24); \
    *(int2*)&xl[b][xw_off] = make_int2(lo_, hi_); }
#define COMPUTE(KS) { \
    v4i xa0 = *(const v4i*)&xl[(KS) & 1][(wm * 2 + 0) * 1024 + lane * 16]; \
    v4i xa1 = *(const v4i*)&xl[(KS) & 1][(wm * 2 + 1) * 1024 + lane * 16]; \
    _Pragma("unroll") for (int ni = 0; ni < 8; ni++) { \
        v4i wb = *(const v4i*)&wl[(KS) & 1][(wn * 8 + ni) * 1024 + lane * 16]; \
        acc[0][ni] = __builtin_amdgcn_mfma_i32_16x16x64_i8(wb, xa0, acc[0][ni], 0, 0, 0); \
        acc[1][ni] = __builtin_amdgcn_mfma_i32_16x16x64_i8(wb, xa1, acc[1][ni], 0, 0, 0); } }
#define STEP_HEAD(KS) if ((KS) + 2 < 8) LOADX((KS) + 2, (KS) & 1);
#define STEP_A(KS) __builtin_amdgcn_s_barrier(); COMPUTE(KS);
#define STEP_B(KS) QUANTX(((KS) + 1) & 1, ((KS) + 1) & 1); WAITLGKM0(); \
    __builtin_amdgcn_s_barrier(); if ((KS) + 2 < 8) DMAW((KS) + 2, (KS) & 1);

    // prologue: queue = [x0:2, x1:2, w0:2, w1:2]
    LOADX(0, 0)
    LOADX(1, 1)
    DMAW(0, 0)
    DMAW(1, 1)
    WAITVM(6);         // x0 landed
    QUANTX(0, 0);
    WAITLGKM0();       // publish bsl/bql + xl[0] before first barrier

    STEP_HEAD(0) WAITVM(4); STEP_A(0) WAITVM(4); STEP_B(0)
    STEP_HEAD(1) WAITVM(6); STEP_A(1) WAITVM(4); STEP_B(1)
    STEP_HEAD(2) WAITVM(6); STEP_A(2) WAITVM(4); STEP_B(2)
    STEP_HEAD(3) WAITVM(6); STEP_A(3) WAITVM(4); STEP_B(3)
    STEP_HEAD(4) WAITVM(6); STEP_A(4) WAITVM(4); STEP_B(4)
    STEP_HEAD(5) WAITVM(6); STEP_A(5) WAITVM(4); STEP_B(5)
    STEP_HEAD(6) WAITVM(4); STEP_A(6) WAITVM(2); STEP_B(6)
    WAITVM(0); STEP_A(7)

    // ---- epilogue: LDS-transposed full-line nt stores, 4 rounds of 32 rows
    __builtin_amdgcn_s_barrier();   // all waves done reading wl/xl
    char* ostage = (char*)wl;       // 32 x 2048B rows = 64 KB
    const int mloc = lane & 15, ocr = (lane >> 4) * 4;
    const char* outb = (char*)out + rbase * 2048 + t * 16;
#pragma unroll
    for (int h = 0; h < 4; h++) {
        if (wm == h) {
#pragma unroll
            for (int ni = 0; ni < 8; ni++) {
                int oc0 = wn * 128 + ni * 16 + ocr;
                float4 s4 = *(const float4*)&bsl[oc0];
                float4 q4 = *(const float4*)&bql[oc0];
#pragma unroll
                for (int mi = 0; mi < 2; mi++) {
                    int row = mi * 16 + mloc;
                    v4f v;
                    v[0] = (float)acc[mi][ni][0] * s4.x + q4.x;
                    v[1] = (float)acc[mi][ni][1] * s4.y + q4.y;
                    v[2] = (float)acc[mi][ni][2] * s4.z + q4.z;
                    v[3] = (float)acc[mi][ni][3] * s4.w + q4.w;
                    int byte = (row * 2048 + oc0 * 4) ^ ((row & 15) << 4);
                    *(v4f*)(ostage + byte) = v;
                }
            }
        }
        WAITLGKM0();
        __builtin_amdgcn_s_barrier();
#pragma unroll
        for (int i = 0; i < 4; i++) {
            int flat = t * 16 + i * 16384;
            int row = flat >> 11;
            v4f v = *(const v4f*)(ostage + (flat ^ ((row & 15) << 4)));
            __builtin_nontemporal_store(v, (v4f*)(outb + h * 65536 + i * 16384));
        }
        if (h < 3) {
            WAITLGKM0();
            __builtin_amdgcn_s_barrier();   // reads done before next round overwrites
        }
    }
#undef LOADX
#undef DMAW
#undef QUANTX
#undef COMPUTE
#undef STEP_HEAD
#undef STEP_A
#undef STEP_B
}

extern "C" void kernel_launch(void* const* d_in, const int* in_sizes, int n_in,
                              void* d_out, int out_size, void* d_ws, size_t ws_size,
                              hipStream_t stream) {
    const float* x    = (const float*)d_in[0];
    const float* w    = (const float*)d_in[1];
    const float* bias = (const float*)d_in[2];
    float* out = (float*)d_out;
    const int M = in_sizes[0] / DIN;   // 65536

    char* ws = (char*)d_ws;
    unsigned* amax = (unsigned*)ws;
    char* wq8  = ws + 64;
    float* wsc = (float*)(wq8 + (long)DOUT * DIN);

    quantw_kernel<<<(DOUT * 64) / 256, 256, 0, stream>>>(w, wq8, wsc, amax);
    absmax_kernel<<<2048, 256, 0, stream>>>((const float4*)x, amax, in_sizes[0] / 4);
    gemm_kernel<<<M / BM, 1024, 0, stream>>>(x, wq8, wsc, bias, amax, out);
}

// Round 24
// 97.352 us; speedup vs baseline: 1.0124x; 1.0124x over previous
//
#include <hip/hip_runtime.h>

#define DIN 512
#define DOUT 512
#define BM 64

typedef int v4i __attribute__((ext_vector_type(4)));
typedef float v4f __attribute__((ext_vector_type(4)));

#define WAITVM(n) asm volatile("s_waitcnt vmcnt(" #n ")" ::: "memory")
#define WAITLGKM0() asm volatile("s_waitcnt lgkmcnt(0)" ::: "memory")

// exact-divide quantize (weights/bias path, matches ref bit-for-bit)
__device__ __forceinline__ int q8f(float v, float s) {
    int i = (int)rintf(v / s);
    i = i < -128 ? -128 : (i > 127 ? 127 : i);
    return i & 255;
}
// multiply-by-reciprocal quantize (activation path; flip prob ~2^-22)
__device__ __forceinline__ int q8m(float v, float inv) {
    int i = (int)rintf(v * inv);
    i = i < -128 ? -128 : (i > 127 ? 127 : i);
    return i & 255;
}

// ---------------- Kernel 1: global absmax of x ----------------
__global__ void absmax_kernel(const float4* __restrict__ x4, unsigned* __restrict__ amax, int n4) {
    float m = 0.f;
    int stride = gridDim.x * blockDim.x;
    for (int i = blockIdx.x * blockDim.x + threadIdx.x; i < n4; i += stride) {
        float4 v = x4[i];
        m = fmaxf(m, fmaxf(fmaxf(fabsf(v.x), fabsf(v.y)), fmaxf(fabsf(v.z), fabsf(v.w))));
    }
#pragma unroll
    for (int off = 32; off; off >>= 1) m = fmaxf(m, __shfl_xor(m, off));
    __shared__ float sm[4];
    int lane = threadIdx.x & 63, w = threadIdx.x >> 6;
    if (lane == 0) sm[w] = m;
    __syncthreads();
    if (threadIdx.x == 0) {
        m = fmaxf(fmaxf(sm[0], sm[1]), fmaxf(sm[2], sm[3]));
        atomicMax(amax, __float_as_uint(m));  // positive floats: uint compare == float compare
    }
}

// ---------------- Kernel 2: weight quant -> frag-linear wq8 (+ amax zero-init) ----------------
// wq8 byte(og,ks,kq,r,b) = og*8192 + ks*1024 + kq*256 + r*16 + b ==> frag (og,ks)
// is CONTIGUOUS 1KB at wq8 + og*8192 + ks*1024 + lane*16. (R12-validated)
__global__ void quantw_kernel(const float* __restrict__ w, char* __restrict__ wq8,
                              float* __restrict__ wsc, unsigned* __restrict__ amax) {
    int gid = blockIdx.x * blockDim.x + threadIdx.x;
    if (gid == 0) *amax = 0u;   // zero-init; absmax launches after quantw on same stream
    int row = gid >> 6, lane = gid & 63;
    const float4* r4 = (const float4*)(w + (long)row * DIN);
    float4 a = r4[lane * 2];
    float4 b = r4[lane * 2 + 1];
    float m = fmaxf(fmaxf(fmaxf(fabsf(a.x), fabsf(a.y)), fabsf(a.z)),
                    fmaxf(fmaxf(fabsf(a.w), fabsf(b.x)),
                          fmaxf(fmaxf(fabsf(b.y), fabsf(b.z)), fabsf(b.w))));
#pragma unroll
    for (int off = 32; off; off >>= 1) m = fmaxf(m, __shfl_xor(m, off));
    float s = m / 127.0f;
    int lo = q8f(a.x, s) | (q8f(a.y, s) << 8) | (q8f(a.z, s) << 16) | (q8f(a.w, s) << 24);
    int hi = q8f(b.x, s) | (q8f(b.y, s) << 8) | (q8f(b.z, s) << 16) | (q8f(b.w, s) << 24);
    {
        int og = row >> 4, r = row & 15;
        int ks = lane >> 3, kq = (lane >> 1) & 3, bo = (lane & 1) * 8;
        *(int2*)(wq8 + og * 8192 + ks * 1024 + kq * 256 + r * 16 + bo) = make_int2(lo, hi);
    }
    if (lane == 0) wsc[row] = s;
}

// ---------------- Kernel 3: R8 skeleton + CONTIGUOUS wq8 DMA (best known: R22) ----------------
// BM=64 x BN=512 (x read once), 512 thr / 8 waves (2m x 4oc), acc 2x8 = 64 VGPR,
// LDS 76KB -> 2 blocks/CU = 16 waves/CU. K-loop: per ks, each wave issues 4
// global_load_lds, each ONE CONTIGUOUS 1KB line of wq8. Counted-vmcnt ladder
// with the wait BEFORE the pre-compute barrier (cross-wave DMA visibility):
// VM1/VM2 = 6,6 / 8,6 x5 / 6,4 / 0. x: in-loop trickle fp32 load + in-register
// quant -> chunk-linear xl dbuf. Epilogue: LDS-transposed full-line nt stores;
// quantb folded into prologue.
__global__ __launch_bounds__(512, 4) void gemm_kernel(
    const float* __restrict__ x, const char* __restrict__ wq8,
    const float* __restrict__ wsc, const float* __restrict__ bias,
    const unsigned* __restrict__ amax, float* __restrict__ out) {
    __shared__ char xl[2][BM * 64];             // 2 x 4 KB x slices
    __shared__ char wl[2][DOUT * 64];           // 2 x 32 KB w slices; reused as ostage
    __shared__ __align__(16) float bsl[512];
    __shared__ __align__(16) float bql[512];
    const int t = threadIdx.x, lane = t & 63, wid = t >> 6;
    const int wm = wid >> 2, wn = wid & 3;
    const long rbase = (long)(gridDim.x - 1 - blockIdx.x) * BM;   // reverse: L3 recency
    const float as = __uint_as_float(*amax) / 127.0f;
    const float inv_as = 1.0f / as;

    // fold quantb: one oc per thread
    {
        float s0 = as * wsc[t];
        bsl[t] = s0;
        bql[t] = rintf(bias[t] / s0) * s0;
    }

    // x staging geometry: thread t -> row t>>3, float4-pair col (t&7)*2
    const int xrow = t >> 3, xc = t & 7;
    const float4* xg = (const float4*)(x + (rbase + xrow) * DIN) + xc * 2;
    const int xw_off = ((xrow >> 4) * 64 + (xc >> 1) * 16 + (xrow & 15)) * 16 + (xc & 1) * 8;

    // w DMA geometry: wave wid stages og chunks wid*4..wid*4+3, CONTIGUOUS 1KB each
    const char* wgsrc = wq8 + (wid * 4) * 8192 + lane * 16;

    float4 xv[2][2];
    v4i acc[2][8] = {};

#define LOADX(n, s) { const float4* p_ = xg + (n) * 16; xv[s][0] = p_[0]; xv[s][1] = p_[1]; }
#define DMAW(n, b) { _Pragma("unroll") for (int jj = 0; jj < 4; jj++) \
    __builtin_amdgcn_global_load_lds( \
        (const __attribute__((address_space(1))) unsigned*)(wgsrc + jj * 8192 + (n) * 1024), \
        (__attribute__((address_space(3))) unsigned*)(wl[b] + (wid * 4 + jj) * 1024), 16, 0, 0); }
#define QUANTX(s, b) { \
    int lo_ = q8m(xv[s][0].x, inv_as) | (q8m(xv[s][0].y, inv_as) << 8) | \
              (q8m(xv[s][0].z, inv_as) << 16) | (q8m(xv[s][0].w, inv_as) << 24); \
    int hi_ = q8m(xv[s][1].x, inv_as) | (q8m(xv[s][1].y, inv_as) << 8) | \
              (q8m(xv[s][1].z, inv_as) << 16) | (q8m(xv[s][1].w, inv_as) << 24); \
    *(int2*)&xl[b][xw_off] = make_int2(lo_, hi_); }
#define COMPUTE(KS) { \
    v4i xa0 = *(const v4i*)&xl[(KS) & 1][(wm * 2 + 0) * 1024 + lane * 16]; \
    v4i xa1 = *(const v4i*)&xl[(KS) & 1][(wm * 2 + 1) * 1024 + lane * 16]; \
    _Pragma("unroll") for (int ni = 0; ni < 8; ni++) { \
        v4i wb = *(const v4i*)&wl[(KS) & 1][(wn * 8 + ni) * 1024 + lane * 16]; \
        acc[0][ni] = __builtin_amdgcn_mfma_i32_16x16x64_i8(wb, xa0, acc[0][ni], 0, 0, 0); \
        acc[1][ni] = __builtin_amdgcn_mfma_i32_16x16x64_i8(wb, xa1, acc[1][ni], 0, 0, 0); } }
#define STEP_HEAD(KS) if ((KS) + 2 < 8) LOADX((KS) + 2, (KS) & 1);
#define STEP_A(KS) __builtin_amdgcn_s_barrier(); COMPUTE(KS);
#define STEP_B(KS) QUANTX(((KS) + 1) & 1, ((KS) + 1) & 1); WAITLGKM0(); \
    __builtin_amdgcn_s_barrier(); if ((KS) + 2 < 8) DMAW((KS) + 2, (KS) & 1);

    // prologue: queue = [x0:2, x1:2, w0:4, w1:4]
    LOADX(0, 0)
    LOADX(1, 1)
    DMAW(0, 0)
    DMAW(1, 1)
    WAITVM(10);        // x0 landed
    QUANTX(0, 0);
    WAITLGKM0();       // publish bsl/bql + xl[0] before first barrier

    STEP_HEAD(0) WAITVM(6); STEP_A(0) WAITVM(6); STEP_B(0)
    STEP_HEAD(1) WAITVM(8); STEP_A(1) WAITVM(6); STEP_B(1)
    STEP_HEAD(2) WAITVM(8); STEP_A(2) WAITVM(6); STEP_B(2)
    STEP_HEAD(3) WAITVM(8); STEP_A(3) WAITVM(6); STEP_B(3)
    STEP_HEAD(4) WAITVM(8); STEP_A(4) WAITVM(6); STEP_B(4)
    STEP_HEAD(5) WAITVM(8); STEP_A(5) WAITVM(6); STEP_B(5)
    STEP_HEAD(6) WAITVM(6); STEP_A(6) WAITVM(4); STEP_B(6)
    WAITVM(0); STEP_A(7)

    // ---- epilogue: LDS-transposed full-line nt stores (R8-validated)
    __builtin_amdgcn_s_barrier();   // all waves done reading wl/xl
    char* ostage = (char*)wl;       // 32 x 2048B rows = 64 KB
    const int mloc = lane & 15, ocr = (lane >> 4) * 4;
    const char* outb = (char*)out + rbase * 2048 + t * 16;
#pragma unroll
    for (int h = 0; h < 2; h++) {
        if (wm == h) {
#pragma unroll
            for (int ni = 0; ni < 8; ni++) {
                int oc0 = wn * 128 + ni * 16 + ocr;
                float4 s4 = *(const float4*)&bsl[oc0];
                float4 q4 = *(const float4*)&bql[oc0];
#pragma unroll
                for (int mi = 0; mi < 2; mi++) {
                    int row = mi * 16 + mloc;
                    v4f v;
                    v[0] = (float)acc[mi][ni][0] * s4.x + q4.x;
                    v[1] = (float)acc[mi][ni][1] * s4.y + q4.y;
                    v[2] = (float)acc[mi][ni][2] * s4.z + q4.z;
                    v[3] = (float)acc[mi][ni][3] * s4.w + q4.w;
                    int byte = (row * 2048 + oc0 * 4) ^ ((row & 15) << 4);
                    *(v4f*)(ostage + byte) = v;
                }
            }
        }
        WAITLGKM0();
        __builtin_amdgcn_s_barrier();
#pragma unroll
        for (int i = 0; i < 8; i++) {
            int flat = t * 16 + i * 8192;
            int row = flat >> 11;
            v4f v = *(const v4f*)(ostage + (flat ^ ((row & 15) << 4)));
            __builtin_nontemporal_store(v, (v4f*)(outb + h * 65536 + i * 8192));
        }
        if (h == 0) {
            WAITLGKM0();
            __builtin_amdgcn_s_barrier();   // reads done before h=1 overwrites
        }
    }
#undef LOADX
#undef DMAW
#undef QUANTX
#undef COMPUTE
#undef STEP_HEAD
#undef STEP_A
#undef STEP_B
}

extern "C" void kernel_launch(void* const* d_in, const int* in_sizes, int n_in,
                              void* d_out, int out_size, void* d_ws, size_t ws_size,
                              hipStream_t stream) {
    const float* x    = (const float*)d_in[0];
    const float* w    = (const float*)d_in[1];
    const float* bias = (const float*)d_in[2];
    float* out = (float*)d_out;
    const int M = in_sizes[0] / DIN;   // 65536

    char* ws = (char*)d_ws;
    unsigned* amax = (unsigned*)ws;
    char* wq8  = ws + 64;
    float* wsc = (float*)(wq8 + (long)DOUT * DIN);

    quantw_kernel<<<(DOUT * 64) / 256, 256, 0, stream>>>(w, wq8, wsc, amax);
    absmax_kernel<<<2048, 256, 0, stream>>>((const float4*)x, amax, in_sizes[0] / 4);
    gemm_kernel<<<M / BM, 512, 0, stream>>>(x, wq8, wsc, bias, amax, out);
}